// Round 1
// 407.448 us; speedup vs baseline: 1.1133x; 1.1133x over previous
//
#include <hip/hip_runtime.h>

#define NN 50000     // nodes
#define NE 800000    // edges
#define DD 64        // channels
#define NG 512       // graphs
#define NL 5         // layers

// ---------------- CSR build v2: two-level bucket sort ----------------
// R10: fill_col_k was 50 us/dispatch with 54.7 MB HBM writes (17x
// amplification: 800K lone 4B stores -> one partial-line writeback each,
// multi-XCD dirty lines). Replace atomic scatter with bucket sort so all
// fine-grained scatter stays inside one block's LDS/L2:
//   bucket b = dst >> 6  (64 nodes/bucket, NBU=782, ~1024 edges avg)
//   K1 histogram (LDS) -> K2 scan -> K3 coarse partition (80B runs,
//   address-adjacent reservations) -> K4 per-bucket finalize (deg/start
//   via LDS prefix, col scatter within a ~4KB single-XCD region).
// K4 also subsumes count_deg_k + calc_start_k.

#define BSH 6
#define NBU ((NN + 63) >> BSH)          // 782
#define EPB 8192                        // edges per block, K1/K3
#define NBLK ((NE + EPB - 1) / EPB)     // 98

__global__ void bucket_count_k(const int* __restrict__ dst, int* __restrict__ bcnt) {
    __shared__ int hist[NBU];
    for (int i = threadIdx.x; i < NBU; i += 256) hist[i] = 0;
    __syncthreads();
    int e0 = blockIdx.x * EPB;
    int e1 = min(e0 + EPB, NE);
    for (int e = e0 + threadIdx.x; e < e1; e += 256)
        atomicAdd(&hist[dst[e] >> BSH], 1);
    __syncthreads();
    for (int i = threadIdx.x; i < NBU; i += 256) {
        int c = hist[i];
        if (c) atomicAdd(&bcnt[i], c);
    }
}

// single wave: exclusive prefix over 782 bucket counts
__global__ void bucket_scan_k(const int* __restrict__ bcnt, int* __restrict__ bstart) {
    int lane = threadIdx.x;
    int carry = 0;
    for (int c = 0; c < NBU; c += 64) {
        int i = c + lane;
        int v = (i < NBU) ? bcnt[i] : 0;
        int incl = v;
#pragma unroll
        for (int off = 1; off < 64; off <<= 1) {
            int t = __shfl_up(incl, off, 64);
            if (lane >= off) incl += t;
        }
        if (i < NBU) bstart[i] = carry + incl - v;
        carry += __shfl(incl, 63, 64);
    }
    if (lane == 0) bstart[NBU] = carry;   // == NE
}

__global__ void bucket_scatter_k(const int* __restrict__ src, const int* __restrict__ dst,
                                 const int* __restrict__ bstart, int* __restrict__ bcur,
                                 int2* __restrict__ ebuf) {
    __shared__ int hist[NBU];
    __shared__ int base[NBU];
    for (int i = threadIdx.x; i < NBU; i += 256) hist[i] = 0;
    __syncthreads();
    int e0 = blockIdx.x * EPB;
    int e1 = min(e0 + EPB, NE);
    for (int e = e0 + threadIdx.x; e < e1; e += 256)
        atomicAdd(&hist[dst[e] >> BSH], 1);
    __syncthreads();
    for (int i = threadIdx.x; i < NBU; i += 256) {
        int c = hist[i];
        base[i] = c ? (bstart[i] + atomicAdd(&bcur[i], c)) : 0;
        hist[i] = 0;
    }
    __syncthreads();
    for (int e = e0 + threadIdx.x; e < e1; e += 256) {
        int s = src[e];
        int d = dst[e];
        int b = d >> BSH;
        int r = atomicAdd(&hist[b], 1);
        ebuf[base[b] + r] = make_int2(s, d);
    }
}

// one block per bucket: per-node deg/start (LDS prefix) + col scatter
__global__ void bucket_finalize_k(const int2* __restrict__ ebuf, const int* __restrict__ bstart,
                                  int* __restrict__ deg, int* __restrict__ start,
                                  int* __restrict__ col) {
    __shared__ int dcnt[64];
    __shared__ int dstart[64];
    const int b = blockIdx.x;
    const int t = threadIdx.x;
    const int s0 = bstart[b], s1 = bstart[b + 1];
    if (t < 64) dcnt[t] = 0;
    __syncthreads();
    for (int i = s0 + t; i < s1; i += 256)
        atomicAdd(&dcnt[ebuf[i].y & 63], 1);
    __syncthreads();
    if (t < 64) {   // wave 0: 64-entry exclusive scan
        int v = dcnt[t];
        int incl = v;
#pragma unroll
        for (int off = 1; off < 64; off <<= 1) {
            int u = __shfl_up(incl, off, 64);
            if (t >= off) incl += u;
        }
        dstart[t] = s0 + incl - v;
        int node = (b << BSH) + t;
        if (node < NN) { deg[node] = v; start[node] = s0 + incl - v; }
        dcnt[t] = 0;
    }
    __syncthreads();
    for (int i = s0 + t; i < s1; i += 256) {
        int2 p = ebuf[i];
        int ln = p.y & 63;
        int r = atomicAdd(&dcnt[ln], 1);
        col[dstart[ln] + r] = p.x;
    }
}

// ---------------- aggregation v5: 32-edge chunks, 8-deep MLP ----------------
// one wave per node; lanes = 4 edge-groups x 16 channel-quads.
// Per 32-edge chunk: ONE col load (lanes 0..31 hold the chunk), nb via
// __shfl; 4 gathers issued unconditionally + 4 more under a wave-uniform
// cnt>16 branch -> up to 8 independent float4 loads in flight before any
// use. (R9 falsified byte-BW-bound; this attacks exposed latency.)
__global__ void aggregate_k(const float* __restrict__ h, const int* __restrict__ start,
                            const int* __restrict__ deg, const int* __restrict__ col,
                            float* __restrict__ agg) {
    int w = (blockIdx.x * blockDim.x + threadIdx.x) >> 6;
    int lane = threadIdx.x & 63;
    if (w >= NN) return;
    int eg = lane >> 4;   // edge group 0..3
    int cl = lane & 15;   // channel quad: floats 4*cl .. 4*cl+3
    int s = start[w], d = deg[w];
    float4 acc0 = make_float4(0.f, 0.f, 0.f, 0.f);
    float4 acc1 = make_float4(0.f, 0.f, 0.f, 0.f);
    const float4* h4 = (const float4*)h;
    for (int base = 0; base < d; base += 32) {
        int idx = base + (lane & 31);
        int cv = col[s + ((idx < d) ? idx : 0)];   // one load, 32 distinct addrs
        int cnt = d - base;                        // >0; wave-uniform
        // first 16 edges of chunk: 4 independent gathers
        float4 v0, v1, v2, v3;
        {
            int n0 = __shfl(cv, eg +  0, 64);
            int n1 = __shfl(cv, eg +  4, 64);
            int n2 = __shfl(cv, eg +  8, 64);
            int n3 = __shfl(cv, eg + 12, 64);
            v0 = h4[(size_t)n0 * 16 + cl];
            v1 = h4[(size_t)n1 * 16 + cl];
            v2 = h4[(size_t)n2 * 16 + cl];
            v3 = h4[(size_t)n3 * 16 + cl];
        }
        float4 v4, v5, v6, v7;
        bool hi = (cnt > 16);                      // wave-uniform branch
        if (hi) {
            int n4 = __shfl(cv, eg + 16, 64);
            int n5 = __shfl(cv, eg + 20, 64);
            int n6 = __shfl(cv, eg + 24, 64);
            int n7 = __shfl(cv, eg + 28, 64);
            v4 = h4[(size_t)n4 * 16 + cl];
            v5 = h4[(size_t)n5 * 16 + cl];
            v6 = h4[(size_t)n6 * 16 + cl];
            v7 = h4[(size_t)n7 * 16 + cl];
        }
        if (eg + 0 < cnt)  { acc0.x += v0.x; acc0.y += v0.y; acc0.z += v0.z; acc0.w += v0.w; }
        if (eg + 4 < cnt)  { acc1.x += v1.x; acc1.y += v1.y; acc1.z += v1.z; acc1.w += v1.w; }
        if (eg + 8 < cnt)  { acc0.x += v2.x; acc0.y += v2.y; acc0.z += v2.z; acc0.w += v2.w; }
        if (eg + 12 < cnt) { acc1.x += v3.x; acc1.y += v3.y; acc1.z += v3.z; acc1.w += v3.w; }
        if (hi) {
            if (eg + 16 < cnt) { acc0.x += v4.x; acc0.y += v4.y; acc0.z += v4.z; acc0.w += v4.w; }
            if (eg + 20 < cnt) { acc1.x += v5.x; acc1.y += v5.y; acc1.z += v5.z; acc1.w += v5.w; }
            if (eg + 24 < cnt) { acc0.x += v6.x; acc0.y += v6.y; acc0.z += v6.z; acc0.w += v6.w; }
            if (eg + 28 < cnt) { acc1.x += v7.x; acc1.y += v7.y; acc1.z += v7.z; acc1.w += v7.w; }
        }
    }
    float4 acc;
    acc.x = acc0.x + acc1.x; acc.y = acc0.y + acc1.y;
    acc.z = acc0.z + acc1.z; acc.w = acc0.w + acc1.w;
#pragma unroll
    for (int off = 16; off <= 32; off <<= 1) {
        acc.x += __shfl_xor(acc.x, off, 64);
        acc.y += __shfl_xor(acc.y, off, 64);
        acc.z += __shfl_xor(acc.z, off, 64);
        acc.w += __shfl_xor(acc.w, off, 64);
    }
    if (eg == 0) {
        ((float4*)(agg + (size_t)w * DD))[cl] = acc;
    }
}

// ---------------- dense layer v4 (proven R5/R7) ----------------
// out = relu([hin] + agg @ Wrel^T + b + hin @ Wroot^T)
// block = 256 = 4 waves, 64 nodes/block. lane = node, wave = 16-output slice.
// Two channel-half passes keep register demand ~105 VGPR (no spill at 3
// blocks/CU). Weights wave-uniform -> scalar s_load; activations in registers.
template <int RESID>
__global__ void __launch_bounds__(256, 3)
dense_layer_k(const float* __restrict__ agg, const float* __restrict__ hin,
              const float* __restrict__ wrel, const float* __restrict__ brel,
              const float* __restrict__ wroot, float* __restrict__ hout) {
    __shared__ float A[64][68];   // stride 68 dwords: b128 transpose reads at 8-phase floor
    __shared__ float H[64][68];

    const int t = threadIdx.x;
    const int tile = blockIdx.x * 64;
    const int nrows = min(64, NN - tile);

    const float4* agg4 = (const float4*)(agg + (size_t)tile * DD);
    const float4* hin4 = (const float4*)(hin + (size_t)tile * DD);
#pragma unroll
    for (int k = 0; k < 4; ++k) {
        int idx = t + k * 256;
        int row = idx >> 4, cq = idx & 15;
        if (row < nrows) {
            *(float4*)&A[row][4 * cq] = agg4[idx];
            *(float4*)&H[row][4 * cq] = hin4[idx];
        }
    }
    __syncthreads();

    const int lane = t & 63;
    const int wv = __builtin_amdgcn_readfirstlane(t >> 6);
    const int o0 = wv * 16;

    float4 a4[8], h4[8];
    float acc[16];

#pragma unroll
    for (int cq = 0; cq < 8; ++cq) {
        a4[cq] = *(const float4*)&A[lane][4 * cq];
        h4[cq] = *(const float4*)&H[lane][4 * cq];
    }
#pragma unroll
    for (int oo = 0; oo < 16; ++oo) {
        int o = o0 + oo;
        const float* w1 = wrel + o * DD;
        const float* w2 = wroot + o * DD;
        float s0 = 0.f, s1 = 0.f, s2 = 0.f, s3 = 0.f;
#pragma unroll
        for (int cq = 0; cq < 8; ++cq) {
            s0 += a4[cq].x * w1[4 * cq + 0] + h4[cq].x * w2[4 * cq + 0];
            s1 += a4[cq].y * w1[4 * cq + 1] + h4[cq].y * w2[4 * cq + 1];
            s2 += a4[cq].z * w1[4 * cq + 2] + h4[cq].z * w2[4 * cq + 2];
            s3 += a4[cq].w * w1[4 * cq + 3] + h4[cq].w * w2[4 * cq + 3];
        }
        acc[oo] = (s0 + s1) + (s2 + s3);
    }

#pragma unroll
    for (int cq = 0; cq < 8; ++cq) {
        a4[cq] = *(const float4*)&A[lane][32 + 4 * cq];
        h4[cq] = *(const float4*)&H[lane][32 + 4 * cq];
    }
    __syncthreads();
    float* Out = &A[0][0];
#pragma unroll
    for (int oo = 0; oo < 16; ++oo) {
        int o = o0 + oo;
        const float* w1 = wrel + o * DD + 32;
        const float* w2 = wroot + o * DD + 32;
        float s0 = acc[oo], s1 = 0.f, s2 = 0.f, s3 = 0.f;
#pragma unroll
        for (int cq = 0; cq < 8; ++cq) {
            s0 += a4[cq].x * w1[4 * cq + 0] + h4[cq].x * w2[4 * cq + 0];
            s1 += a4[cq].y * w1[4 * cq + 1] + h4[cq].y * w2[4 * cq + 1];
            s2 += a4[cq].z * w1[4 * cq + 2] + h4[cq].z * w2[4 * cq + 2];
            s3 += a4[cq].w * w1[4 * cq + 3] + h4[cq].w * w2[4 * cq + 3];
        }
        Out[lane * 68 + o] = (s0 + s1) + (s2 + s3) + brel[o];
    }
    __syncthreads();

    float4* out4 = (float4*)(hout + (size_t)tile * DD);
#pragma unroll
    for (int k = 0; k < 4; ++k) {
        int idx = t + k * 256;
        int row = idx >> 4, cq = idx & 15;
        if (row < nrows) {
            float4 r = *(const float4*)&A[row][4 * cq];
            if (RESID) {
                float4 hr = *(const float4*)&H[row][4 * cq];
                r.x += hr.x; r.y += hr.y; r.z += hr.z; r.w += hr.w;
            }
            r.x = fmaxf(r.x, 0.f); r.y = fmaxf(r.y, 0.f);
            r.z = fmaxf(r.z, 0.f); r.w = fmaxf(r.w, 0.f);
            out4[idx] = r;
        }
    }
}

// ---------------- pooling (batch is sorted) ----------------

__global__ void pool_k(const float* __restrict__ h, const int* __restrict__ batch,
                       float* __restrict__ sums, int* __restrict__ cnt) {
    const int NP = 32;
    int w = (blockIdx.x * blockDim.x + threadIdx.x) >> 6;
    int lane = threadIdx.x & 63;
    int n0 = w * NP;
    if (n0 >= NN) return;
    int n1 = min(n0 + NP, NN);
    int g = batch[n0];
    float acc = 0.f;
    int run = 0;
    for (int i = n0; i < n1; ++i) {
        int gi = batch[i];
        if (gi != g) {
            atomicAdd(&sums[g * DD + lane], acc);
            if (lane == 0) atomicAdd(&cnt[g], run);
            acc = 0.f; run = 0; g = gi;
        }
        acc += h[i * DD + lane];
        run++;
    }
    atomicAdd(&sums[g * DD + lane], acc);
    if (lane == 0) atomicAdd(&cnt[g], run);
}

// ---------------- head: mean -> linear -> softmax ----------------

__global__ void head_k(const float* __restrict__ sums, const int* __restrict__ cnt,
                       const float* __restrict__ lin_w, const float* __restrict__ lin_b,
                       float* __restrict__ out) {
    int g = blockIdx.x * (blockDim.x >> 6) + (threadIdx.x >> 6);
    int o = threadIdx.x & 63;
    if (g >= NG) return;
    float c = (float)cnt[g];
    float inv = 1.0f / fmaxf(c, 1.0f);
    float acc = lin_b[o];
#pragma unroll 8
    for (int k = 0; k < DD; ++k) {
        acc += sums[g * DD + k] * inv * lin_w[o * DD + k];
    }
    float m = acc;
#pragma unroll
    for (int off = 32; off; off >>= 1) m = fmaxf(m, __shfl_xor(m, off, 64));
    float e = __expf(acc - m);
    float s = e;
#pragma unroll
    for (int off = 32; off; off >>= 1) s += __shfl_xor(s, off, 64);
    out[g * DD + o] = e / s;
}

// ---------------- driver ----------------

extern "C" void kernel_launch(void* const* d_in, const int* in_sizes, int n_in,
                              void* d_out, int out_size, void* d_ws, size_t ws_size,
                              hipStream_t stream) {
    const float* x      = (const float*)d_in[0];
    const int*   edge   = (const int*)d_in[1];   // [2, E]: src = edge, dst = edge+NE
    const int*   batch  = (const int*)d_in[2];
    const float* rel_w  = (const float*)d_in[3]; // [L, D, D]
    const float* rel_b  = (const float*)d_in[4]; // [L, D]
    const float* root_w = (const float*)d_in[5]; // [L, D, D]
    const float* lin_w  = (const float*)d_in[6]; // [D, D]
    const float* lin_b  = (const float*)d_in[7]; // [D]
    float* out = (float*)d_out;

    const int* src = edge;
    const int* dst = edge + NE;

    // workspace carve (all 256B aligned)
    char* p = (char*)d_ws;
    auto carve = [&](size_t bytes) {
        char* r = p;
        p += (bytes + 255) & ~(size_t)255;
        return (void*)r;
    };
    float* hA    = (float*)carve((size_t)NN * DD * 4);
    float* hB    = (float*)carve((size_t)NN * DD * 4);
    float* agg   = (float*)carve((size_t)NN * DD * 4);
    int*   col   = (int*)carve((size_t)NE * 4);
    int*   strt  = (int*)carve((size_t)NN * 4);
    int*   deg   = (int*)carve((size_t)NN * 4);
    int*   bstart= (int*)carve((size_t)(NBU + 1) * 4);
    // ---- contiguous zero region (single memset) ----
    char* zbase = p;
    float* sums = (float*)carve((size_t)NG * DD * 4);
    int*   cnt  = (int*)carve((size_t)NG * 4);
    int*   bcnt = (int*)carve((size_t)NBU * 4);
    int*   bcur = (int*)carve((size_t)NBU * 4);
    size_t zbytes = (size_t)(p - zbase);

    // ebuf (6.4 MB of (src,dst) pairs) aliases agg (12.8 MB): agg is dead
    // until layer-0 aggregate, which runs after the CSR build completes.
    int2* ebuf = (int2*)agg;

    hipMemsetAsync(zbase, 0, zbytes, stream);

    // CSR build v2 (bucket sort; subsumes count_deg/calc_start/fill_col)
    bucket_count_k<<<NBLK, 256, 0, stream>>>(dst, bcnt);
    bucket_scan_k<<<1, 64, 0, stream>>>(bcnt, bstart);
    bucket_scatter_k<<<NBLK, 256, 0, stream>>>(src, dst, bstart, bcur, ebuf);
    bucket_finalize_k<<<NBU, 256, 0, stream>>>(ebuf, bstart, deg, strt, col);

    const int aggBlocks = (NN + 3) / 4;     // 4 waves (nodes) per block
    const int dnsBlocks = (NN + 63) / 64;   // 64 nodes per block

    // layer 0: x -> hA
    aggregate_k<<<aggBlocks, 256, 0, stream>>>(x, strt, deg, col, agg);
    dense_layer_k<0><<<dnsBlocks, 256, 0, stream>>>(agg, x, rel_w, rel_b, root_w, hA);
    // layer 1: hA -> hB
    aggregate_k<<<aggBlocks, 256, 0, stream>>>(hA, strt, deg, col, agg);
    dense_layer_k<0><<<dnsBlocks, 256, 0, stream>>>(agg, hA, rel_w + 4096, rel_b + 64,
                                                    root_w + 4096, hB);
    // layer 2: hB -> hA
    aggregate_k<<<aggBlocks, 256, 0, stream>>>(hB, strt, deg, col, agg);
    dense_layer_k<0><<<dnsBlocks, 256, 0, stream>>>(agg, hB, rel_w + 2 * 4096, rel_b + 2 * 64,
                                                    root_w + 2 * 4096, hA);
    // layer 3 (residual): hA -> hB
    aggregate_k<<<aggBlocks, 256, 0, stream>>>(hA, strt, deg, col, agg);
    dense_layer_k<1><<<dnsBlocks, 256, 0, stream>>>(agg, hA, rel_w + 3 * 4096, rel_b + 3 * 64,
                                                    root_w + 3 * 4096, hB);
    // layer 4 (residual): hB -> hA
    aggregate_k<<<aggBlocks, 256, 0, stream>>>(hB, strt, deg, col, agg);
    dense_layer_k<1><<<dnsBlocks, 256, 0, stream>>>(agg, hB, rel_w + 4 * 4096, rel_b + 4 * 64,
                                                    root_w + 4 * 4096, hA);

    // pool + head
    const int wavesPool = (NN + 31) / 32;
    pool_k<<<(wavesPool + 3) / 4, 256, 0, stream>>>(hA, batch, sums, cnt);
    head_k<<<(NG + 3) / 4, 256, 0, stream>>>(sums, cnt, lin_w, lin_b, out);
}